// Round 5
// baseline (179.954 us; speedup 1.0000x reference)
//
#include <hip/hip_runtime.h>

// ConvCapsMatrix EM routing, MI355X. Inputs FP32, output FP32.
// R22: FUSED single-launch. One block per pos (576 blocks x 512 threads) owns
// all 288 n's -> the EM cross-n reduction is block-local, so all 3 iterations
// + final output run in ONE kernel. Eliminates the measured ~35us (22%) of
// inter-launch overhead: 3 launch gaps, 2x x/a re-staging, ~20MB/iter partial
// global round-trips, and the separate final kernel. d_ws unused.
// Post-mortem R21: pk cut ~40% of j-body VALU instrs -> only -3% wall
// (160.1us). With R19b (3x waves -> worse) and R20 (unroll -> spill), the
// j-body is latency-chain-bound; instruction count and wave supply are
// exhausted levers. The remaining big cost was between kernels, not in them.
// Residency plan: LDS 43.6KB (x3 = 131 <= 160KB/CU) and __launch_bounds__
// (512,3) -> VGPR cap ~84 (R20 confirmed blocks/CU semantics: arg 4 => 64
// pin). 3 blocks/CU => 768 slots >= 576 => no straggler wave. Scalar j-body
// (proven 64 VGPR, fits cap; pk needs ~110+ and would spill under 84).
// GUARDRAIL: WRITE_SIZE must be ~1.3MB (Out only); tens of MB => spills.

#define EPSV 1e-8f

template <int CTRL>
__device__ __forceinline__ float dppf(float v) {
  return __int_as_float(__builtin_amdgcn_update_dpp(
      0, __float_as_int(v), CTRL, 0xf, 0xf, true));
}
__device__ __forceinline__ float swz16(float v) {   // lane ^ 16 within 32-groups
  return __int_as_float(__builtin_amdgcn_ds_swizzle(__float_as_int(v), 0x401F));
}
__device__ __forceinline__ float red_max32(float v) {
  v = fmaxf(v, dppf<0xB1>(v));
  v = fmaxf(v, dppf<0x4E>(v));
  v = fmaxf(v, dppf<0x141>(v));
  v = fmaxf(v, dppf<0x140>(v));
  v = fmaxf(v, swz16(v));
  return v;
}
__device__ __forceinline__ float red_sum32(float v) {
  v += dppf<0xB1>(v);
  v += dppf<0x4E>(v);
  v += dppf<0x141>(v);
  v += dppf<0x140>(v);
  v += swz16(v);
  return v;
}

__device__ __forceinline__ void compute_votes(const float* __restrict__ Wt,
                                              const float* __restrict__ xr,
                                              int n, int o, float* __restrict__ V)
{
  // W[k,l,c,o,y,z] flat = (n*32+o)*16 + y*4+z ; xr = local pose row (16 f)
  float Wf[16];
  {
    const float* wp = Wt + (((n << 5) + o) << 4);
#pragma unroll
    for (int i = 0; i < 4; ++i) {
      const float4 q = *(const float4*)(wp + (i << 2));
      Wf[i*4+0]=q.x; Wf[i*4+1]=q.y; Wf[i*4+2]=q.z; Wf[i*4+3]=q.w;
    }
  }
  float xv[16];
#pragma unroll
  for (int i = 0; i < 4; ++i) {
    const float4 q = *(const float4*)(xr + (i << 2));
    xv[i*4+0]=q.x; xv[i*4+1]=q.y; xv[i*4+2]=q.z; xv[i*4+3]=q.w;
  }
#pragma unroll
  for (int xi = 0; xi < 4; ++xi)
#pragma unroll
    for (int z = 0; z < 4; ++z)
      V[xi*4+z] = fmaf(xv[xi*4+0], Wf[z],
                  fmaf(xv[xi*4+1], Wf[4+z],
                  fmaf(xv[xi*4+2], Wf[8+z],
                       xv[xi*4+3]* Wf[12+z])));
}

// ---- fused kernel: one block per pos; all 3 EM iterations + output.
__global__ __launch_bounds__(512, 3) void caps_fused(
    const float* __restrict__ X, const float* __restrict__ A,
    const float* __restrict__ Wt, const float* __restrict__ Bu,
    const float* __restrict__ Ba, float* __restrict__ Out)
{
  __shared__ float xp_s[288*16];   // all 288 pose rows          18432 B
  __shared__ float a_s[288];       // activations                 1152 B
  __shared__ float part[8*544];    // per-wave partials, 2-phase 17408 B
  __shared__ float prs[8*32];      // per-wave sum Ra             1024 B
  __shared__ float mu_t[512], isig_t[512], lsig_t[512];        // 6144 B
  __shared__ float la_s[32], slog_s[32], rs_s[32], aout_s[32]; //  512 B

  const int t    = threadIdx.x;
  const int o    = t & 31;
  const int ng   = t >> 5;        // 0..15
  const int wv   = t >> 6;        // 0..7
  const int lane = t & 63;

  const int pos = blockIdx.x;
  const int b  = pos / 144;
  const int r_ = pos - b*144;
  const int h  = r_ / 12;
  const int w  = r_ - (r_/12)*12;

  // ---- stage ALL 288 pose rows + activations (once, lives across all iters)
  for (int i = t; i < 1152; i += 512) {      // 1152 float4 chunks
    const int r  = i >> 2, q4 = i & 3;
    const int kl = r >> 5, c = r & 31;
    const int hy = h + kl/3, wx = w + (kl - (kl/3)*3);
    const float4 v = *(const float4*)(X + ((((b*14+hy)*14+wx) << 9) + (c << 4) + (q4 << 2)));
    *(float4*)(xp_s + (r << 4) + (q4 << 2)) = v;
  }
  if (t < 288) {
    const int kl = t >> 5, c = t & 31;
    const int hy = h + kl/3, wx = w + (kl - (kl/3)*3);
    a_s[t] = A[((b*14+hy)*14+wx)*32 + c];
  }
  __syncthreads();

  float mu_r[16], isig_r[16];
  float la_r = 0.f, slog_r = 0.f;
#pragma unroll
  for (int p = 0; p < 16; ++p) { mu_r[p] = 0.f; isig_r[p] = 0.f; }

#pragma unroll 1
  for (int it = 0; it < 3; ++it) {
    // ---- fused stats pass over all 288 n's
    float S1[16], S2[16];
#pragma unroll
    for (int p = 0; p < 16; ++p) { S1[p] = 0.f; S2[p] = 0.f; }
    float rs = 0.f;

#pragma unroll 1
    for (int j = 0; j < 18; ++j) {
      const int nl = ng + (j << 4);         // n = 0..287
      float V[16];
      compute_votes(Wt, xp_s + (nl << 4), nl, o, V);

      float ra;
      if (it == 0) {
        ra = a_s[nl] * (1.0f/32.0f);
      } else {
        float q0 = 0.f, q1 = 0.f, q2 = 0.f, q3 = 0.f;
#pragma unroll
        for (int p = 0; p < 4; ++p) {
          float d;
          d = V[p]    - mu_r[p];    q0 = fmaf(d*d, isig_r[p],    q0);
          d = V[p+4]  - mu_r[p+4];  q1 = fmaf(d*d, isig_r[p+4],  q1);
          d = V[p+8]  - mu_r[p+8];  q2 = fmaf(d*d, isig_r[p+8],  q2);
          d = V[p+12] - mu_r[p+12]; q3 = fmaf(d*d, isig_r[p+12], q3);
        }
        const float q = slog_r + ((q0 + q1) + (q2 + q3));
        const float z = la_r - 0.5f*q;
        const float m  = red_max32(z);
        const float ev = __expf(z - m);
        const float s  = red_sum32(ev);
        ra = (ev / s) * a_s[nl];
      }
      rs += ra;
#pragma unroll
      for (int p = 0; p < 16; ++p) {
        const float rv = ra * V[p];
        S1[p] += rv;
        S2[p] = fmaf(rv, V[p], S2[p]);
      }
    }

    // ---- pair-combine ng via lane^32
#pragma unroll
    for (int p = 0; p < 16; ++p) {
      S1[p] += __shfl_xor(S1[p], 32);
      S2[p] += __shfl_xor(S2[p], 32);
    }
    rs += __shfl_xor(rs, 32);

    // ---- phase A: S1 partials + rs -> block-wide sums
    if (lane < 32) {
      float* p1 = part + wv*544 + o*17;
#pragma unroll
      for (int p = 0; p < 16; ++p) p1[p] = S1[p];
      prs[wv*32 + o] = rs;
    }
    __syncthreads();
    float s1v;
    {
      const int pi = t >> 5, oo = t & 31;
      float s1 = 0.f;
#pragma unroll
      for (int g = 0; g < 8; ++g) s1 += part[g*544 + oo*17 + pi];
      s1v = s1;
      if (t < 32) {
        float r = 0.f;
#pragma unroll
        for (int g = 0; g < 8; ++g) r += prs[(g << 5) + t];
        rs_s[t] = r + EPSV;
      }
    }
    __syncthreads();                        // part reusable; rs_s visible

    // ---- phase B: S2 partials -> block-wide sums, then state
    if (lane < 32) {
      float* p2 = part + wv*544 + o*17;
#pragma unroll
      for (int p = 0; p < 16; ++p) p2[p] = S2[p];
    }
    __syncthreads();
    {
      const int pi = t >> 5, oo = t & 31;
      float s2 = 0.f;
#pragma unroll
      for (int g = 0; g < 8; ++g) s2 += part[g*544 + oo*17 + pi];
      const float rsum = rs_s[oo];
      const float mu = s1v / rsum;
      float var = s2 / rsum - mu*mu;
      var = fmaxf(var, 0.f);
      const float sg = var + EPSV;
      mu_t[t]   = mu;                       // t == pi*32+oo
      isig_t[t] = 1.0f / sg;
      lsig_t[t] = __logf(sg);
    }
    __syncthreads();
    if (t < 32) {
      float slog = 0.f;
#pragma unroll
      for (int p = 0; p < 16; ++p) slog += lsig_t[p*32 + t];
      const float cost = rs_s[t] * (16.0f*Bu[t] + 0.5f*slog);
      const float av = 1.0f / (1.0f + __expf(-(Ba[t] - cost)));   // LAM=1
      la_s[t]   = __logf(av + EPSV);
      slog_s[t] = slog;
      aout_s[t] = av;
    }
    __syncthreads();
    if (it < 2) {
#pragma unroll
      for (int p = 0; p < 16; ++p) { mu_r[p] = mu_t[p*32 + o]; isig_r[p] = isig_t[p*32 + o]; }
      slog_r = slog_s[o];
      la_r   = la_s[o];
    }
  }

  // ---- output: pose (o-major, p-minor) + activations
  {
    const int oo = t >> 4, pi = t & 15;
    Out[pos*512 + t] = mu_t[pi*32 + oo];
  }
  if (t < 32) Out[294912 + pos*32 + t] = aout_s[t];
}

extern "C" void kernel_launch(void* const* d_in, const int* in_sizes, int n_in,
                              void* d_out, int out_size, void* d_ws, size_t ws_size,
                              hipStream_t stream) {
  (void)in_sizes; (void)n_in; (void)d_ws; (void)ws_size; (void)out_size;
  const float* X  = (const float*)d_in[0];
  const float* A  = (const float*)d_in[1];
  const float* Wt = (const float*)d_in[2];
  const float* Bu = (const float*)d_in[3];
  const float* Ba = (const float*)d_in[4];
  float* Out = (float*)d_out;

  hipLaunchKernelGGL(caps_fused, dim3(576), dim3(512), 0, stream,
                     X, A, Wt, Bu, Ba, Out);
}